// Round 1
// baseline (96.160 us; speedup 1.0000x reference)
//
#include <hip/hip_runtime.h>

// YOLO layer decode: (B, nA*(nC+5), g, g) f32 -> (B, nA*g*g, nC+5) f32
// B=64, nA=3, nC=80, g=52, stride = img_dim/g = 8.
//
// Memory-bound transpose + pointwise transcendental. LDS-tiled transpose:
//   load:  float4 along spatial axis (coalesced), scatter to lds[s*85+c]
//   store: lds is linear in output element index -> ds_read_b128 + float4 store

#define G_     52
#define S_     (G_ * G_)       // 2704
#define NA_    3
#define C_     85              // nC + 5
#define B_     64
#define TS_    64              // spatial positions per tile
#define NTILES ((S_ + TS_ - 1) / TS_)   // 43 (42 full + 1 tail of 16)

__global__ __launch_bounds__(256) void yolo_decode_kernel(
    const float* __restrict__ x,
    const int*   __restrict__ img_dim_p,
    float*       __restrict__ out)
{
    __shared__ float lds[TS_ * C_];   // 21760 B

    const int tile = blockIdx.x;
    const int a    = blockIdx.y;
    const int b    = blockIdx.z;
    const int s0   = tile * TS_;
    const int tid  = threadIdx.x;

    // img_dim may arrive as int32 or float32 bits; disambiguate.
    int   bits = img_dim_p[0];
    float img  = (bits > 0 && bits < (1 << 20)) ? (float)bits
                                                : __int_as_float(bits);
    const float stride = img / (float)G_;   // 8.0

    // anchors (compile-time)
    const float aw  = (a == 0) ? 10.0f : (a == 1) ? 16.0f : 33.0f;
    const float ah  = (a == 0) ? 13.0f : (a == 1) ? 30.0f : 23.0f;
    const float saw = aw / stride;          // scaled anchor (matches reference)
    const float sah = ah / stride;

    const float* inb = x + (size_t)(b * NA_ + a) * C_ * S_;
    const int ns = min(TS_, S_ - s0);       // 64 or 16 (tail)
    const int nq = ns >> 2;                 // float4s per channel in this tile

    // ---- load phase: coalesced float4 along spatial, scatter to LDS ----
    for (int t = tid; t < C_ * (TS_ >> 2); t += 256) {
        const int c  = t >> 4;              // t / 16
        const int sq = t & 15;
        if (sq < nq) {
            const float4 v = *reinterpret_cast<const float4*>(
                inb + (size_t)c * S_ + s0 + 4 * sq);
            const int sl = 4 * sq;
            lds[(sl    ) * C_ + c] = v.x;
            lds[(sl + 1) * C_ + c] = v.y;
            lds[(sl + 2) * C_ + c] = v.z;
            lds[(sl + 3) * C_ + c] = v.w;
        }
    }
    __syncthreads();

    // ---- store phase: linear ds_read_b128, pointwise math, float4 store ----
    const int nvals = ns * C_;              // 5440 or 1360, both % 4 == 0
    float* outb = out + ((size_t)(b * NA_ + a) * S_ + s0) * C_;

    for (int u = tid; 4 * u < nvals; u += 256) {
        const int e0 = 4 * u;
        const float4 vin = *reinterpret_cast<const float4*>(&lds[e0]);

        int sl = e0 / 85;
        int k  = e0 - 85 * sl;

        float4 r;
        const float* vp = &vin.x;
        float*       rp = &r.x;
        #pragma unroll
        for (int m = 0; m < 4; ++m) {
            const float v = vp[m];
            float val;
            if (k >= 4) {
                val = 1.0f / (1.0f + __expf(-v));           // cls / conf
            } else if (k == 0) {
                const int sg = s0 + sl;
                const int j  = sg % G_;                      // grid_x
                val = (1.0f / (1.0f + __expf(-v)) + (float)j) * stride;
            } else if (k == 1) {
                const int sg = s0 + sl;
                const int i  = sg / G_;                      // grid_y
                val = (1.0f / (1.0f + __expf(-v)) + (float)i) * stride;
            } else if (k == 2) {
                val = __expf(v) * saw * stride;
            } else {  // k == 3
                val = __expf(v) * sah * stride;
            }
            rp[m] = val;
            // advance (sl, k) for next element
            if (++k == 85) { k = 0; ++sl; }
        }
        *reinterpret_cast<float4*>(outb + e0) = r;
    }
}

extern "C" void kernel_launch(void* const* d_in, const int* in_sizes, int n_in,
                              void* d_out, int out_size, void* d_ws, size_t ws_size,
                              hipStream_t stream)
{
    const float* x   = (const float*)d_in[0];
    const int*   img = (const int*)d_in[1];
    float*       out = (float*)d_out;

    dim3 grid(NTILES, NA_, B_);
    dim3 block(256);
    yolo_decode_kernel<<<grid, block, 0, stream>>>(x, img, out);
}

// Round 2
// 70.965 us; speedup vs baseline: 1.3550x; 1.3550x over previous
//
#include <hip/hip_runtime.h>

// YOLO layer decode: (B, nA*(nC+5), g, g) f32 -> (B, nA*g*g, nC+5) f32
// B=64, nA=3, nC=80, g=52, stride = img_dim/g = 8.
//
// Memory-bound transpose + pointwise transcendental.
// R2: all math done in the LOAD phase (channel-major, branch on c is
// near-wave-uniform), single-instruction rcp/exp2 for sigmoid; store phase
// is a pure LDS->global copy (ds_read_b128 + global_store_dwordx4).

#define G_     52
#define S_     (G_ * G_)       // 2704
#define NA_    3
#define C_     85              // nC + 5
#define B_     64
#define TS_    64              // spatial positions per tile
#define NTILES ((S_ + TS_ - 1) / TS_)   // 43 (42 full + 1 tail of 16)

#define LOG2E_ 1.44269504088896340736f

__device__ __forceinline__ float fast_sigmoid(float v) {
    // 1/(1+e^-v) = rcp(1 + 2^(-v*log2e)); v_exp_f32 + v_rcp_f32, ~1 ulp each
    float e = __builtin_amdgcn_exp2f(-LOG2E_ * v);
    return __builtin_amdgcn_rcpf(1.0f + e);
}

__global__ __launch_bounds__(256) void yolo_decode_kernel(
    const float* __restrict__ x,
    const int*   __restrict__ img_dim_p,
    float*       __restrict__ out)
{
    __shared__ float lds[TS_ * C_];   // 21760 B

    const int tile = blockIdx.x;
    const int a    = blockIdx.y;
    const int b    = blockIdx.z;
    const int s0   = tile * TS_;
    const int tid  = threadIdx.x;

    // img_dim may arrive as int32 or float32 bits; disambiguate.
    int   bits = img_dim_p[0];
    float img  = (bits > 0 && bits < (1 << 20)) ? (float)bits
                                                : __int_as_float(bits);
    const float stride = img / (float)G_;   // 8.0

    // anchors (compile-time); fold stride: (a/stride)*stride == a exactly
    const float aw = (a == 0) ? 10.0f : (a == 1) ? 16.0f : 33.0f;
    const float ah = (a == 0) ? 13.0f : (a == 1) ? 30.0f : 23.0f;

    const float* inb = x + (size_t)(b * NA_ + a) * C_ * S_;
    const int ns = min(TS_, S_ - s0);       // 64 or 16 (tail)
    const int nq = ns >> 2;                 // float4s per channel in this tile

    // ---- load+math phase: coalesced float4 along spatial, math, scatter ----
    for (int t = tid; t < C_ * (TS_ >> 2); t += 256) {
        const int c  = t >> 4;              // channel: near-wave-uniform
        const int sq = t & 15;
        if (sq < nq) {
            float4 v = *reinterpret_cast<const float4*>(
                inb + (size_t)c * S_ + s0 + 4 * sq);
            float* vp = &v.x;

            if (c >= 4) {
                // conf + cls: plain sigmoid (the 81/85 common path)
                #pragma unroll
                for (int m = 0; m < 4; ++m) vp[m] = fast_sigmoid(vp[m]);
            } else if (c == 0) {
                #pragma unroll
                for (int m = 0; m < 4; ++m) {
                    const int sg = s0 + 4 * sq + m;
                    const int j  = sg % G_;              // grid_x
                    vp[m] = (fast_sigmoid(vp[m]) + (float)j) * stride;
                }
            } else if (c == 1) {
                #pragma unroll
                for (int m = 0; m < 4; ++m) {
                    const int sg = s0 + 4 * sq + m;
                    const int i  = sg / G_;              // grid_y
                    vp[m] = (fast_sigmoid(vp[m]) + (float)i) * stride;
                }
            } else if (c == 2) {
                #pragma unroll
                for (int m = 0; m < 4; ++m)
                    vp[m] = __builtin_amdgcn_exp2f(LOG2E_ * vp[m]) * aw;
            } else {  // c == 3
                #pragma unroll
                for (int m = 0; m < 4; ++m)
                    vp[m] = __builtin_amdgcn_exp2f(LOG2E_ * vp[m]) * ah;
            }

            const int sl = 4 * sq;
            lds[(sl    ) * C_ + c] = v.x;
            lds[(sl + 1) * C_ + c] = v.y;
            lds[(sl + 2) * C_ + c] = v.z;
            lds[(sl + 3) * C_ + c] = v.w;
        }
    }
    __syncthreads();

    // ---- store phase: pure copy, ds_read_b128 + coalesced float4 store ----
    const int nq4 = (ns * C_) >> 2;         // 1360 or 340
    float* outb = out + ((size_t)(b * NA_ + a) * S_ + s0) * C_;

    for (int u = tid; u < nq4; u += 256) {
        const float4 v = *reinterpret_cast<const float4*>(&lds[4 * u]);
        *reinterpret_cast<float4*>(outb + 4 * u) = v;
    }
}

extern "C" void kernel_launch(void* const* d_in, const int* in_sizes, int n_in,
                              void* d_out, int out_size, void* d_ws, size_t ws_size,
                              hipStream_t stream)
{
    const float* x   = (const float*)d_in[0];
    const int*   img = (const int*)d_in[1];
    float*       out = (float*)d_out;

    dim3 grid(NTILES, NA_, B_);
    dim3 block(256);
    yolo_decode_kernel<<<grid, block, 0, stream>>>(x, img, out);
}

// Round 4
// 64.254 us; speedup vs baseline: 1.4966x; 1.1044x over previous
//
#include <hip/hip_runtime.h>

// YOLO layer decode: (B, nA*(nC+5), g, g) f32 -> (B, nA*g*g, nC+5) f32
// B=64, nA=3, nC=80, g=52, stride = img_dim/g = 8.
//
// R4 = R3 with the nontemporal-store type fixed (clang ext_vector_type
// instead of HIP_vector_type float4, which the builtin rejects).
// R3 theory: batched loads (all 6 float4s in flight before LDS writes) break
// the load->ds_write latency chain; nontemporal output stores keep the
// (replay-reused) input resident in L2/L3.

#define G_     52
#define S_     (G_ * G_)       // 2704
#define NA_    3
#define C_     85              // nC + 5
#define B_     64
#define TS_    64              // spatial positions per tile
#define NTILES ((S_ + TS_ - 1) / TS_)   // 43 (42 full + 1 tail of 16)

#define LOG2E_ 1.44269504088896340736f

typedef float f32x4 __attribute__((ext_vector_type(4)));

__device__ __forceinline__ float fast_sigmoid(float v) {
    // 1/(1+e^-v) = rcp(1 + 2^(-v*log2e)); v_exp_f32 + v_rcp_f32, ~1 ulp each
    float e = __builtin_amdgcn_exp2f(-LOG2E_ * v);
    return __builtin_amdgcn_rcpf(1.0f + e);
}

__global__ __launch_bounds__(256) void yolo_decode_kernel(
    const float* __restrict__ x,
    const int*   __restrict__ img_dim_p,
    float*       __restrict__ out)
{
    __shared__ float lds[TS_ * C_];   // 21760 B -> 7 blocks/CU

    const int tile = blockIdx.x;
    const int a    = blockIdx.y;
    const int b    = blockIdx.z;
    const int s0   = tile * TS_;
    const int tid  = threadIdx.x;

    // img_dim may arrive as int32 or float32 bits; disambiguate.
    int   bits = img_dim_p[0];
    float img  = (bits > 0 && bits < (1 << 20)) ? (float)bits
                                                : __int_as_float(bits);
    const float stride = img / (float)G_;   // 8.0

    // anchors (compile-time); (anchor/stride)*stride folds back exactly
    const float aw = (a == 0) ? 10.0f : (a == 1) ? 16.0f : 33.0f;
    const float ah = (a == 0) ? 13.0f : (a == 1) ? 30.0f : 23.0f;

    const float* inb = x + (size_t)(b * NA_ + a) * (size_t)(C_ * S_);

    if (tile != NTILES - 1) {
        // ---------- full tile: 64 positions, 85*16 = 1360 float4 items ----------
        // 6 iterations of 256 threads; last covers tid < 80.
        f32x4 r[6];
        #pragma unroll
        for (int i = 0; i < 6; ++i) {
            const int t = tid + 256 * i;
            if (i < 5 || tid < 80) {
                const int c  = t >> 4;
                const int sq = t & 15;
                r[i] = *reinterpret_cast<const f32x4*>(
                    inb + (size_t)c * S_ + s0 + 4 * sq);
            }
        }
        #pragma unroll
        for (int i = 0; i < 6; ++i) {
            const int t = tid + 256 * i;
            if (i < 5 || tid < 80) {
                const int c  = t >> 4;      // near-wave-uniform
                const int sq = t & 15;
                f32x4 v = r[i];
                if (c >= 4) {
                    #pragma unroll
                    for (int m = 0; m < 4; ++m) v[m] = fast_sigmoid(v[m]);
                } else if (c == 0) {
                    #pragma unroll
                    for (int m = 0; m < 4; ++m) {
                        const int sg = s0 + 4 * sq + m;
                        v[m] = (fast_sigmoid(v[m]) + (float)(sg % G_)) * stride;
                    }
                } else if (c == 1) {
                    #pragma unroll
                    for (int m = 0; m < 4; ++m) {
                        const int sg = s0 + 4 * sq + m;
                        v[m] = (fast_sigmoid(v[m]) + (float)(sg / G_)) * stride;
                    }
                } else if (c == 2) {
                    #pragma unroll
                    for (int m = 0; m < 4; ++m)
                        v[m] = __builtin_amdgcn_exp2f(LOG2E_ * v[m]) * aw;
                } else {  // c == 3
                    #pragma unroll
                    for (int m = 0; m < 4; ++m)
                        v[m] = __builtin_amdgcn_exp2f(LOG2E_ * v[m]) * ah;
                }
                const int sl = 4 * sq;
                lds[(sl    ) * C_ + c] = v[0];
                lds[(sl + 1) * C_ + c] = v[1];
                lds[(sl + 2) * C_ + c] = v[2];
                lds[(sl + 3) * C_ + c] = v[3];
            }
        }
    } else {
        // ---------- tail tile: 16 positions, 85*4 = 340 float4 items ----------
        for (int t = tid; t < C_ * 4; t += 256) {
            const int c  = t >> 2;
            const int sq = t & 3;
            f32x4 v = *reinterpret_cast<const f32x4*>(
                inb + (size_t)c * S_ + s0 + 4 * sq);
            if (c >= 4) {
                #pragma unroll
                for (int m = 0; m < 4; ++m) v[m] = fast_sigmoid(v[m]);
            } else if (c == 0) {
                #pragma unroll
                for (int m = 0; m < 4; ++m) {
                    const int sg = s0 + 4 * sq + m;
                    v[m] = (fast_sigmoid(v[m]) + (float)(sg % G_)) * stride;
                }
            } else if (c == 1) {
                #pragma unroll
                for (int m = 0; m < 4; ++m) {
                    const int sg = s0 + 4 * sq + m;
                    v[m] = (fast_sigmoid(v[m]) + (float)(sg / G_)) * stride;
                }
            } else if (c == 2) {
                #pragma unroll
                for (int m = 0; m < 4; ++m)
                    v[m] = __builtin_amdgcn_exp2f(LOG2E_ * v[m]) * aw;
            } else {
                #pragma unroll
                for (int m = 0; m < 4; ++m)
                    v[m] = __builtin_amdgcn_exp2f(LOG2E_ * v[m]) * ah;
            }
            const int sl = 4 * sq;
            lds[(sl    ) * C_ + c] = v[0];
            lds[(sl + 1) * C_ + c] = v[1];
            lds[(sl + 2) * C_ + c] = v[2];
            lds[(sl + 3) * C_ + c] = v[3];
        }
    }
    __syncthreads();

    // ---- store phase: pure copy, ds_read_b128 + nontemporal float4 store ----
    float* outb = out + ((size_t)(b * NA_ + a) * S_ + s0) * C_;

    if (tile != NTILES - 1) {
        #pragma unroll
        for (int i = 0; i < 6; ++i) {
            const int u = tid + 256 * i;    // 1360 float4s
            if (i < 5 || tid < 80) {
                const f32x4 v = *reinterpret_cast<const f32x4*>(&lds[4 * u]);
                __builtin_nontemporal_store(v, reinterpret_cast<f32x4*>(outb + 4 * u));
            }
        }
    } else {
        for (int u = tid; u < 340; u += 256) {
            const f32x4 v = *reinterpret_cast<const f32x4*>(&lds[4 * u]);
            __builtin_nontemporal_store(v, reinterpret_cast<f32x4*>(outb + 4 * u));
        }
    }
}

extern "C" void kernel_launch(void* const* d_in, const int* in_sizes, int n_in,
                              void* d_out, int out_size, void* d_ws, size_t ws_size,
                              hipStream_t stream)
{
    const float* x   = (const float*)d_in[0];
    const int*   img = (const int*)d_in[1];
    float*       out = (float*)d_out;

    dim3 grid(NTILES, NA_, B_);
    dim3 block(256);
    yolo_decode_kernel<<<grid, block, 0, stream>>>(x, img, out);
}

// Round 5
// 63.351 us; speedup vs baseline: 1.5179x; 1.0143x over previous
//
#include <hip/hip_runtime.h>

// YOLO layer decode: (B, nA*(nC+5), g, g) f32 -> (B, nA*g*g, nC+5) f32
// B=64, nA=3, nC=80, g=52, stride = img_dim/g = 8.
//
// R5: persistent 4-row blocks, double-buffered LDS (one g=52 row per buffer),
// register prefetch of row r+1 issued before a RAW s_barrier that waits only
// lgkmcnt(0) (not vmcnt) -> global loads stay in flight across the barrier,
// overlapping the store phase. __syncthreads would drain vmcnt(0) and
// serialize read/store streams (the R4 limit).

#define G_        52
#define S_        2704                 // 52*52
#define NA_       3
#define C_        85                   // nC + 5
#define B_        64
#define ROW_WORDS (G_ * C_)            // 4420 floats per row-tile
#define ITEMS     (ROW_WORDS / 4)      // 1105 float4 items per row
#define ROWS_PB   4                    // rows per block; 13 blocks * 4 = 52
#define LOG2E_    1.44269504088896340736f

typedef float f32x4 __attribute__((ext_vector_type(4)));

__device__ __forceinline__ float fast_sigmoid(float v) {
    // 1/(1+e^-v) = rcp(1 + 2^(-v*log2e)); v_exp_f32 + v_rcp_f32
    float e = __builtin_amdgcn_exp2f(-LOG2E_ * v);
    return __builtin_amdgcn_rcpf(1.0f + e);
}

__global__ __launch_bounds__(256) void yolo_decode_kernel(
    const float* __restrict__ x,
    const int*   __restrict__ img_dim_p,
    float*       __restrict__ out)
{
    __shared__ float lds[2][ROW_WORDS];   // 35360 B -> 4 blocks/CU

    const int rb  = blockIdx.x;           // 0..12
    const int a   = blockIdx.y;
    const int b   = blockIdx.z;
    const int tid = threadIdx.x;
    const int row0 = rb * ROWS_PB;

    // img_dim may arrive as int32 or float32 bits; disambiguate.
    int   bits = img_dim_p[0];
    float img  = (bits > 0 && bits < (1 << 20)) ? (float)bits
                                                : __int_as_float(bits);
    const float stride = img / (float)G_;   // 8.0

    const float aw = (a == 0) ? 10.0f : (a == 1) ? 16.0f : 33.0f;
    const float ah = (a == 0) ? 13.0f : (a == 1) ? 30.0f : 23.0f;

    const float* inb   = x   + (size_t)(b * NA_ + a) * (size_t)(C_ * S_);
    float*       outb0 = out + (size_t)(b * NA_ + a) * (size_t)S_ * C_;

    // Row-invariant per-thread decomposition: item q -> (channel c, quad sq)
    int c_[5], sq_[5];
    #pragma unroll
    for (int i = 0; i < 5; ++i) {
        const int q = tid + 256 * i;
        c_[i]  = q / 13;                  // magic-mul div
        sq_[i] = q - 13 * c_[i];
    }
    const bool act4 = (tid < ITEMS - 1024);   // 81 threads active in slot 4

    f32x4 regs[5];

    // prologue: load row0
    #pragma unroll
    for (int i = 0; i < 5; ++i)
        if (i < 4 || act4)
            regs[i] = *reinterpret_cast<const f32x4*>(
                inb + (size_t)c_[i] * S_ + row0 * G_ + 4 * sq_[i]);

    for (int r = 0; r < ROWS_PB; ++r) {
        const int row  = row0 + r;
        float*    buf  = lds[r & 1];
        const float rowf = (float)row;    // grid_y for this whole row

        // ---- math + transpose-scatter into LDS (consumes regs) ----
        #pragma unroll
        for (int i = 0; i < 5; ++i) {
            if (i < 4 || act4) {
                const int c  = c_[i];     // near-wave-uniform
                const int sq = sq_[i];
                f32x4 v = regs[i];
                if (c >= 4) {
                    #pragma unroll
                    for (int m = 0; m < 4; ++m) v[m] = fast_sigmoid(v[m]);
                } else if (c == 0) {
                    #pragma unroll
                    for (int m = 0; m < 4; ++m)
                        v[m] = (fast_sigmoid(v[m]) + (float)(4 * sq + m)) * stride;
                } else if (c == 1) {
                    #pragma unroll
                    for (int m = 0; m < 4; ++m)
                        v[m] = (fast_sigmoid(v[m]) + rowf) * stride;
                } else if (c == 2) {
                    #pragma unroll
                    for (int m = 0; m < 4; ++m)
                        v[m] = __builtin_amdgcn_exp2f(LOG2E_ * v[m]) * aw;
                } else {  // c == 3
                    #pragma unroll
                    for (int m = 0; m < 4; ++m)
                        v[m] = __builtin_amdgcn_exp2f(LOG2E_ * v[m]) * ah;
                }
                const int base = 4 * sq * C_ + c;
                buf[base         ] = v[0];
                buf[base +     C_] = v[1];
                buf[base + 2 * C_] = v[2];
                buf[base + 3 * C_] = v[3];
            }
        }

        // ---- prefetch row r+1 (stays in flight across the raw barrier) ----
        if (r + 1 < ROWS_PB) {
            #pragma unroll
            for (int i = 0; i < 5; ++i)
                if (i < 4 || act4)
                    regs[i] = *reinterpret_cast<const f32x4*>(
                        inb + (size_t)c_[i] * S_ + (row + 1) * G_ + 4 * sq_[i]);
        }

        // ---- barrier: order LDS only; do NOT drain vmcnt (keep prefetch
        //      loads + prior stores in flight). All waves execute this. ----
        asm volatile("s_waitcnt lgkmcnt(0)" ::: "memory");
        __builtin_amdgcn_s_barrier();

        // ---- store phase: linear ds_read_b128 + coalesced NT stores ----
        float* outr = outb0 + (size_t)row * ROW_WORDS;
        #pragma unroll
        for (int i = 0; i < 5; ++i) {
            if (i < 4 || act4) {
                const int q = tid + 256 * i;
                const f32x4 v = *reinterpret_cast<const f32x4*>(&buf[4 * q]);
                __builtin_nontemporal_store(v, reinterpret_cast<f32x4*>(outr + 4 * q));
            }
        }
        // next iteration's ds_write targets the other buffer; its WAR on this
        // buffer is protected by the next iteration's lgkmcnt(0)+barrier.
    }
}

extern "C" void kernel_launch(void* const* d_in, const int* in_sizes, int n_in,
                              void* d_out, int out_size, void* d_ws, size_t ws_size,
                              hipStream_t stream)
{
    const float* x   = (const float*)d_in[0];
    const int*   img = (const int*)d_in[1];
    float*       out = (float*)d_out;

    dim3 grid(G_ / ROWS_PB / 1, NA_, B_);   // (13, 3, 64)
    dim3 block(256);
    yolo_decode_kernel<<<dim3(13, NA_, B_), block, 0, stream>>>(x, img, out);
}